// Round 2
// baseline (351.482 us; speedup 1.0000x reference)
//
#include <hip/hip_runtime.h>
#include <hip/hip_bf16.h>

// Problem: out[b,o,hw] = sum_c W[o,c] * relu(x[b,c,hw]*scale[c] + shift[c])
// B=256, Cin=2112, Cout=192, HW=49. ALL tensors fp32 in device memory
// (reference dtypes). Internally: BN+ReLU fused into LDS staging, values
// rounded to bf16, bf16 MFMA 16x16x32 with fp32 accumulate, fp32 stores.
//
// Per batch: C(192x49) = W(192x2112) . h(2112x49).
// W = A-operand direct from global (k-contiguous rows), cvt fp32->bf16 per use.
// x = B-operand via BN-fused transposed LDS tile with XOR-rotate swizzle.

#define CIN   2112
#define COUT  192
#define HWS   49
#define BK    32
#define MB    96      // Cout rows per block (2 blocks per batch)
#define NSTEP (CIN / BK)   // 66
#define EPSV  1e-5f

typedef __bf16 bf16;
typedef __attribute__((ext_vector_type(8))) __bf16 bf16x8;
typedef __attribute__((ext_vector_type(4))) float  f32x4;

__global__ __launch_bounds__(256, 2)
void bnrelu_conv1x1_kernel(const float* __restrict__ x,
                           const float* __restrict__ gamma,
                           const float* __restrict__ beta,
                           const float* __restrict__ rmean,
                           const float* __restrict__ rvar,
                           const float* __restrict__ W,
                           float* __restrict__ out)
{
    __shared__ float2 ss[CIN + 8];                 // (scale, shift) per channel
    __shared__ __align__(16) bf16 btile[64 * BK];  // [hw 0..63][c 0..31], swizzled

    const int tid   = threadIdx.x;
    const int b     = blockIdx.x >> 1;
    const int mbase = (blockIdx.x & 1) * MB;

    // ---- one-time: zero btile (cols 49..63 stay zero forever) ----
    {
        bf16x8 z;
        #pragma unroll
        for (int j = 0; j < 8; j++) z[j] = (bf16)0.0f;
        ((bf16x8*)btile)[tid] = z;   // 256 chunks of 8 == 64*32 exactly
    }

    // ---- one-time: precompute BN scale/shift into LDS ----
    for (int c = tid; c < CIN; c += 256) {
        float g  = gamma[c];
        float be = beta[c];
        float mu = rmean[c];
        float va = rvar[c];
        float inv = rsqrtf(va + EPSV);
        float s  = g * inv;
        ss[c] = make_float2(s, be - mu * s);
    }
    if (tid < 8) ss[CIN + tid] = make_float2(0.f, 0.f);  // pad for c0+1 lookups

    const float* xb = x + (size_t)b * (CIN * HWS);

    const int lane = tid & 63;
    const int wv   = tid >> 6;   // wave id == n-tile id
    const int l15  = lane & 15;
    const int q    = lane >> 4;  // k-quad

    // accumulators: 6 m-tiles x 1 n-tile per wave
    f32x4 acc[6];
    #pragma unroll
    for (int i = 0; i < 6; i++) acc[i] = (f32x4)(0.f);

    // per-lane W fragment base pointers (A-operand: m=lane&15, k=q*8+j)
    const float* wp[6];
    #pragma unroll
    for (int mt = 0; mt < 6; mt++)
        wp[mt] = W + (size_t)(mbase + mt * 16 + l15) * CIN + q * 8;

    // LDS B-fragment read address (B-operand: n=lane&15 -> hw, k=q*8+j)
    const int hwr  = wv * 16 + l15;
    const int rotR = (q + (hwr >> 2)) & 3;
    const bf16* brd = &btile[hwr * BK + rotR * 8];

    __syncthreads();  // btile zeros + ss ready

    for (int ks = 0; ks < NSTEP; ks++) {
        const int k0 = ks * BK;

        // ---- stage: 32 channels x 49 hw = 1568 floats = 196 threads x 8 ----
        if (ks) __syncthreads();   // previous iteration's B-frag reads done
        if (tid < 196) {
            const int fb = k0 * HWS + tid * 8;
            f32x4 xv0 = *(const f32x4*)(xb + fb);
            f32x4 xv1 = *(const f32x4*)(xb + fb + 4);
            int c0  = fb / 49;             // magic-mul div by constant
            int hw0 = fb - c0 * 49;
            float2 sA = ss[c0];
            float2 sB = ss[c0 + 1];
            #pragma unroll
            for (int j = 0; j < 8; j++) {
                float xj = (j < 4) ? xv0[j] : xv1[j - 4];
                int hw = hw0 + j;
                int c  = c0;
                float2 sc = sA;
                if (hw >= HWS) { hw -= HWS; c += 1; sc = sB; }  // at most one wrap
                float v = fmaxf(xj * sc.x + sc.y, 0.f);
                const int cl = c - k0;                 // 0..31 always in-tile
                const int cg = cl >> 3, ci = cl & 7;
                const int rot = (cg + (hw >> 2)) & 3;  // bank swizzle
                btile[hw * BK + rot * 8 + ci] = (bf16)v;
            }
        }
        __syncthreads();

        // ---- compute ----
        bf16x8 bfrag = *(const bf16x8*)brd;
        #pragma unroll
        for (int mt = 0; mt < 6; mt++) {
            const float* w = wp[mt] + k0;
            f32x4 w0 = *(const f32x4*)w;
            f32x4 w1 = *(const f32x4*)(w + 4);
            bf16x8 afrag;
            #pragma unroll
            for (int j = 0; j < 4; j++) { afrag[j] = (bf16)w0[j]; afrag[j + 4] = (bf16)w1[j]; }
            acc[mt] = __builtin_amdgcn_mfma_f32_16x16x32_bf16(afrag, bfrag, acc[mt], 0, 0, 0);
        }
    }

    // ---- epilogue: C/D layout col=lane&15 (hw), row=q*4+r (m) ----
    const int hw = wv * 16 + l15;
    if (hw < HWS) {
        #pragma unroll
        for (int mt = 0; mt < 6; mt++) {
            #pragma unroll
            for (int r = 0; r < 4; r++) {
                const int row = mbase + mt * 16 + q * 4 + r;
                out[((size_t)b * COUT + row) * HWS + hw] = acc[mt][r];
            }
        }
    }
}

extern "C" void kernel_launch(void* const* d_in, const int* in_sizes, int n_in,
                              void* d_out, int out_size, void* d_ws, size_t ws_size,
                              hipStream_t stream) {
    const float* x     = (const float*)d_in[0];
    const float* gamma = (const float*)d_in[1];
    const float* beta  = (const float*)d_in[2];
    const float* rmean = (const float*)d_in[3];
    const float* rvar  = (const float*)d_in[4];
    const float* W     = (const float*)d_in[5];
    float* out = (float*)d_out;

    bnrelu_conv1x1_kernel<<<dim3(512), dim3(256), 0, stream>>>(
        x, gamma, beta, rmean, rvar, W, out);
}

// Round 3
// 346.267 us; speedup vs baseline: 1.0151x; 1.0151x over previous
//
#include <hip/hip_runtime.h>
#include <hip/hip_bf16.h>

// out[b,o,hw] = sum_c W[o,c] * relu(x[b,c,hw]*scale[c] + shift[c])
// B=256, Cin=2112, Cout=192, HW=49, all fp32 in HBM. bf16 MFMA internally.
//
// R3: grid 1024 (4 Cout-splits/batch, M=48), 4 blocks/CU, double-buffered
// btile with ONE barrier per K-step, register prefetch of x(k+1)/W(k+1)
// issued after the barrier (HIP drains vmcnt at __syncthreads), k-invariant
// staging addresses hoisted out of the loop.

#define CIN   2112
#define COUT  192
#define HWS   49
#define BK    32
#define MB    48            // Cout rows per block (4 blocks per batch)
#define NSTEP (CIN / BK)    // 66
#define EPSV  1e-5f
#define TILE_E (64 * BK)    // 2048 bf16 elements per buffer

typedef __bf16 bf16;
typedef __attribute__((ext_vector_type(8))) __bf16 bf16x8;
typedef __attribute__((ext_vector_type(4))) float  f32x4;

__global__ __launch_bounds__(256, 4)
void bnrelu_conv1x1_kernel(const float* __restrict__ x,
                           const float* __restrict__ gamma,
                           const float* __restrict__ beta,
                           const float* __restrict__ rmean,
                           const float* __restrict__ rvar,
                           const float* __restrict__ W,
                           float* __restrict__ out)
{
    __shared__ float2 ss[CIN + 2];                       // (scale, shift)
    __shared__ __align__(16) bf16 btile[2][TILE_E];      // double-buffered

    const int tid   = threadIdx.x;
    const int b     = blockIdx.x >> 2;
    const int mbase = (blockIdx.x & 3) * MB;

    // ---- one-time: BN scale/shift into LDS ----
    for (int c = tid; c < CIN; c += 256) {
        float inv = rsqrtf(rvar[c] + EPSV);
        float s   = gamma[c] * inv;
        ss[c] = make_float2(s, beta[c] - rmean[c] * s);
    }
    if (tid < 2) ss[CIN + tid] = make_float2(0.f, 0.f);

    const int lane = tid & 63;
    const int wv   = tid >> 6;
    const int l15  = lane & 15;
    const int q    = lane >> 4;

    // ---- k-invariant staging setup (196*8 == 32*49 exactly) ----
    const bool stage = tid < 196;
    int addrs[8];
    int jwTh = 8;          // first j that wraps to next channel (8 = none)
    {
        const int off = tid * 8;
        const int cl0 = off / 49;
        const int hw0 = off - cl0 * 49;
        if (hw0 + 8 > HWS) jwTh = HWS - hw0;
        #pragma unroll
        for (int j = 0; j < 8; j++) {
            int hw = hw0 + j, cl = cl0;
            if (hw >= HWS) { hw -= HWS; cl += 1; }
            const int rot = ((cl >> 3) + (hw >> 2)) & 3;
            addrs[j] = hw * BK + rot * 8 + (cl & 7);
        }
        // note: cl0 used below for ssp
    }
    const int cl0 = (tid * 8) / 49;
    const float2* ssp = &ss[cl0];

    const float* xptr = x + (size_t)b * (CIN * HWS) + tid * 8;

    // W fragment pointers (A-operand: m=lane&15, k=q*8+j)
    const float* wpt[3];
    #pragma unroll
    for (int mt = 0; mt < 3; mt++)
        wpt[mt] = W + (size_t)(mbase + mt * 16 + l15) * CIN + q * 8;

    // B-fragment LDS read offset (n=l15 -> hw row = wv*16+l15, cg=q)
    const int hwr    = wv * 16 + l15;
    const int brdoff = hwr * BK + ((q + (hwr >> 2)) & 3) * 8;

    // ---- prime the pipeline: x step 0, W k0=0 ----
    f32x4 xv0, xv1;
    if (stage) { xv0 = *(const f32x4*)xptr; xv1 = *(const f32x4*)(xptr + 4); }
    f32x4 wA[3], wB[3];
    #pragma unroll
    for (int mt = 0; mt < 3; mt++) {
        wA[mt] = *(const f32x4*)wpt[mt];
        wB[mt] = *(const f32x4*)(wpt[mt] + 4);
    }

    f32x4 acc[3];
    #pragma unroll
    for (int i = 0; i < 3; i++) acc[i] = (f32x4)(0.f);

    __syncthreads();   // ss ready

    int p = 0;
    for (int ks = 0; ks < NSTEP; ks++) {
        // ---- stage current x regs -> btile[p] (BN+ReLU+cvt) ----
        if (stage) {
            const float2 s0 = ssp[0];
            const float2 s1 = ssp[1];
            ssp += BK;
            bf16* bt = btile[p];
            #pragma unroll
            for (int j = 0; j < 8; j++) {
                const float xj = (j < 4) ? xv0[j] : xv1[j - 4];
                const float sc = (j >= jwTh) ? s1.x : s0.x;
                const float sh = (j >= jwTh) ? s1.y : s0.y;
                bt[addrs[j]] = (bf16)fmaxf(fmaf(xj, sc, sh), 0.f);
            }
        }

        // ---- cvt current W regs -> bf16 A-fragments (frees W regs) ----
        bf16x8 af[3];
        #pragma unroll
        for (int mt = 0; mt < 3; mt++) {
            #pragma unroll
            for (int j = 0; j < 4; j++) {
                af[mt][j]     = (bf16)wA[mt][j];
                af[mt][j + 4] = (bf16)wB[mt][j];
            }
        }

        __syncthreads();   // btile[p] visible; prior reads of btile[p^1] done

        // ---- prefetch next step (after barrier so loads stay in flight) ----
        if (ks + 1 < NSTEP) {
            xptr += BK * HWS;
            if (stage) { xv0 = *(const f32x4*)xptr; xv1 = *(const f32x4*)(xptr + 4); }
            #pragma unroll
            for (int mt = 0; mt < 3; mt++) {
                wpt[mt] += BK;
                wA[mt] = *(const f32x4*)wpt[mt];
                wB[mt] = *(const f32x4*)(wpt[mt] + 4);
            }
        }

        // ---- compute ----
        const bf16x8 bfrag = *(const bf16x8*)(btile[p] + brdoff);
        #pragma unroll
        for (int mt = 0; mt < 3; mt++)
            acc[mt] = __builtin_amdgcn_mfma_f32_16x16x32_bf16(af[mt], bfrag, acc[mt], 0, 0, 0);

        p ^= 1;
    }

    // ---- epilogue: C/D layout col=lane&15 (hw), row=q*4+r ----
    const int hw = wv * 16 + l15;
    if (hw < HWS) {
        #pragma unroll
        for (int mt = 0; mt < 3; mt++) {
            #pragma unroll
            for (int r = 0; r < 4; r++) {
                const int row = mbase + mt * 16 + q * 4 + r;
                out[((size_t)b * COUT + row) * HWS + hw] = acc[mt][r];
            }
        }
    }
}

extern "C" void kernel_launch(void* const* d_in, const int* in_sizes, int n_in,
                              void* d_out, int out_size, void* d_ws, size_t ws_size,
                              hipStream_t stream) {
    const float* x     = (const float*)d_in[0];
    const float* gamma = (const float*)d_in[1];
    const float* beta  = (const float*)d_in[2];
    const float* rmean = (const float*)d_in[3];
    const float* rvar  = (const float*)d_in[4];
    const float* W     = (const float*)d_in[5];
    float* out = (float*)d_out;

    bnrelu_conv1x1_kernel<<<dim3(1024), dim3(256), 0, stream>>>(
        x, gamma, beta, rmean, rvar, W, out);
}

// Round 4
// 222.289 us; speedup vs baseline: 1.5812x; 1.5577x over previous
//
#include <hip/hip_runtime.h>
#include <hip/hip_bf16.h>

// out[b,o,hw] = sum_c W[o,c] * relu(x[b,c,hw]*scale[c] + shift[c])
// B=256, Cin=2112, Cout=192, HW=49, all fp32 in HBM. bf16 MFMA internally.
//
// R4: barrier-free K-loop. Each wave owns an hw-window (0/11/22/33 + 0..15)
// and gathers its B-fragment DIRECTLY into registers (8 k-strided dwords,
// 4x64B segments per instr). BN+ReLU applied in-register. W pre-repacked to
// bf16 A-fragment order by a tiny pre-kernel (1 dwordx4/lane/m-tile, L1-hot).
// Deep prefetch rings (x depth-3, Wb depth-2) keep HBM queues full per
// Little's law. Only one __syncthreads in the whole kernel (ss table init).

#define CIN   2112
#define COUT  192
#define HWS   49
#define BK    32
#define NSTEP (CIN / BK)   // 66
#define EPSV  1e-5f

typedef __bf16 bf16;
typedef __attribute__((ext_vector_type(8))) __bf16 bf16x8;
typedef __attribute__((ext_vector_type(4))) float  f32x4;

// ---------- kernel 1: W fp32 -> bf16 in A-fragment order ----------
// Wb[((ks*12 + gmt)*64 + lane)*8 + j] = W[(gmt*16+(lane&15))*CIN + ks*32+(lane>>4)*8+j]
__global__ __launch_bounds__(256)
void w_repack_kernel(const float* __restrict__ W, bf16* __restrict__ Wb) {
    const int t = blockIdx.x * 256 + threadIdx.x;       // 66*12*64 = 50688
    if (t >= NSTEP * 12 * 64) return;
    const int lane = t & 63;
    const int gmt  = (t >> 6) % 12;
    const int ks   = t / (12 * 64);
    const int row  = gmt * 16 + (lane & 15);
    const int k    = ks * BK + (lane >> 4) * 8;
    const float* src = W + (size_t)row * CIN + k;
    f32x4 a = *(const f32x4*)src;
    f32x4 b = *(const f32x4*)(src + 4);
    bf16x8 o;
    #pragma unroll
    for (int j = 0; j < 4; j++) { o[j] = (bf16)a[j]; o[j + 4] = (bf16)b[j]; }
    *(bf16x8*)(Wb + (size_t)t * 8) = o;
}

// ---------- kernel 2: main GEMM ----------
__global__ __launch_bounds__(256, 2)
void bnrelu_conv1x1_kernel(const float* __restrict__ x,
                           const float* __restrict__ gamma,
                           const float* __restrict__ beta,
                           const float* __restrict__ rmean,
                           const float* __restrict__ rvar,
                           const bf16*  __restrict__ Wb,
                           float* __restrict__ out)
{
    __shared__ __align__(16) float ssf[2 * CIN];   // [2c]=scale, [2c+1]=shift

    const int tid  = threadIdx.x;
    const int b    = blockIdx.x >> 1;
    const int half = blockIdx.x & 1;               // Cout split: rows half*96..
    const int gmt0 = half * 6;                     // first global m-tile

    // one-time BN table
    for (int c = tid; c < CIN; c += 256) {
        float inv = rsqrtf(rvar[c] + EPSV);
        float s   = gamma[c] * inv;
        ssf[2 * c]     = s;
        ssf[2 * c + 1] = beta[c] - rmean[c] * s;
    }

    const int lane = tid & 63;
    const int wv   = tid >> 6;       // wave id -> hw window
    const int l15  = lane & 15;
    const int q    = lane >> 4;
    const int hw0  = wv * 11;        // windows 0-15,11-26,22-37,33-48 cover 0..48

    // per-lane bases
    const float* xL  = x + (size_t)b * (CIN * HWS) + (q * 8) * HWS + hw0 + l15;
    const bf16*  wbL = Wb + ((size_t)gmt0 * 64 + lane) * 8;
    const float* ssq = ssf + q * 16;  // this lane's 8 (scale,shift) pairs start

    f32x4 acc[6];
    #pragma unroll
    for (int i = 0; i < 6; i++) acc[i] = (f32x4)(0.f);

    // ---- prefetch rings: x depth 3, Wb depth 2 ----
    float  xr[3][8];
    bf16x8 wr[2][6];
    #pragma unroll
    for (int d = 0; d < 3; d++) {
        const float* p = xL + d * (BK * HWS);
        #pragma unroll
        for (int j = 0; j < 8; j++) xr[d][j] = p[j * HWS];
    }
    #pragma unroll
    for (int d = 0; d < 2; d++) {
        const bf16* p = wbL + (size_t)d * (12 * 64 * 8);
        #pragma unroll
        for (int mt = 0; mt < 6; mt++) wr[d][mt] = *(const bf16x8*)(p + mt * (64 * 8));
    }

    __syncthreads();   // ssf ready (only barrier in the kernel)

    #pragma unroll 6
    for (int ks = 0; ks < NSTEP; ks++) {
        const int s3 = ks % 3;
        const int s2 = ks & 1;

        // BN params for this step's 8 channels (broadcast LDS reads)
        const float* sb = ssq + ks * 64;
        f32x4 p0 = *(const f32x4*)(sb);
        f32x4 p1 = *(const f32x4*)(sb + 4);
        f32x4 p2 = *(const f32x4*)(sb + 8);
        f32x4 p3 = *(const f32x4*)(sb + 12);
        float sc[8], sh[8];
        sc[0]=p0[0]; sh[0]=p0[1]; sc[1]=p0[2]; sh[1]=p0[3];
        sc[2]=p1[0]; sh[2]=p1[1]; sc[3]=p1[2]; sh[3]=p1[3];
        sc[4]=p2[0]; sh[4]=p2[1]; sc[5]=p2[2]; sh[5]=p2[3];
        sc[6]=p3[0]; sh[6]=p3[1]; sc[7]=p3[2]; sh[7]=p3[3];

        // consume x ring -> B-fragment (BN + ReLU + cvt)
        bf16x8 bfrag;
        #pragma unroll
        for (int j = 0; j < 8; j++) {
            float v = fmaxf(fmaf(xr[s3][j], sc[j], sh[j]), 0.f);
            bfrag[j] = (bf16)v;
        }

        // refill x ring with step ks+3 (clamped; duplicate tail loads unused)
        {
            int kf = ks + 3; if (kf > NSTEP - 1) kf = NSTEP - 1;
            const float* p = xL + kf * (BK * HWS);
            #pragma unroll
            for (int j = 0; j < 8; j++) xr[s3][j] = p[j * HWS];
        }

        // MFMA: 6 m-tiles
        #pragma unroll
        for (int mt = 0; mt < 6; mt++)
            acc[mt] = __builtin_amdgcn_mfma_f32_16x16x32_bf16(wr[s2][mt], bfrag, acc[mt], 0, 0, 0);

        // refill Wb ring with step ks+2 (clamped)
        {
            int kf = ks + 2; if (kf > NSTEP - 1) kf = NSTEP - 1;
            const bf16* p = wbL + (size_t)kf * (12 * 64 * 8);
            #pragma unroll
            for (int mt = 0; mt < 6; mt++) wr[s2][mt] = *(const bf16x8*)(p + mt * (64 * 8));
        }
    }

    // epilogue: C/D layout col=lane&15 -> hw, row=q*4+r -> m
    // overlapping windows write duplicate columns with identical values (benign)
    const int hw = hw0 + l15;                    // <= 48 always
    const int mbase = half * 96;
    #pragma unroll
    for (int mt = 0; mt < 6; mt++) {
        #pragma unroll
        for (int r = 0; r < 4; r++) {
            const int row = mbase + mt * 16 + q * 4 + r;
            out[((size_t)b * COUT + row) * HWS + hw] = acc[mt][r];
        }
    }
}

extern "C" void kernel_launch(void* const* d_in, const int* in_sizes, int n_in,
                              void* d_out, int out_size, void* d_ws, size_t ws_size,
                              hipStream_t stream) {
    const float* x     = (const float*)d_in[0];
    const float* gamma = (const float*)d_in[1];
    const float* beta  = (const float*)d_in[2];
    const float* rmean = (const float*)d_in[3];
    const float* rvar  = (const float*)d_in[4];
    const float* W     = (const float*)d_in[5];
    float* out = (float*)d_out;

    bf16* Wb = (bf16*)d_ws;   // 66*12*64*8 bf16 = 811008 B of scratch

    w_repack_kernel<<<dim3(198), dim3(256), 0, stream>>>(W, Wb);
    bnrelu_conv1x1_kernel<<<dim3(512), dim3(256), 0, stream>>>(
        x, gamma, beta, rmean, rvar, Wb, out);
}